// Round 7
// baseline (39.638 us; speedup 1.0000x reference)
//
#include <hip/hip_runtime.h>

#define NN 512
#define DD 9
#define LL 32
#define NT 32   // 16x16 tiles per dimension

typedef _Float16 f16x8 __attribute__((ext_vector_type(8)));
typedef float    f32x4 __attribute__((ext_vector_type(4)));
typedef unsigned long long u64;

__device__ __forceinline__ u64 umin64(u64 a, u64 b) { return a < b ? a : b; }

// Generic min-pass: wave owns row-tiles {2w,2w+1} of the "a side", scans all 32
// "b side" tiles. d = na[row] + nb[col] + cross via MFMA (hi/lo f16 split, exact
// products). u64 key (dbits<<32)|col: unsigned min == lexicographic (d, first
// index). Every output row has a unique writer -> direct store, no atomics.
__device__ __forceinline__ void min_pass(const f16x8* __restrict__ sAs,
                                         const f16x8* __restrict__ sBs,
                                         const float* __restrict__ na,
                                         const float* __restrict__ nb,
                                         u64* __restrict__ out_arr,
                                         int wave, int lane)
{
    const int ti0 = wave * 2;
    f16x8 afr[2];
    int   rowb[2];
    float x2r[8];
    #pragma unroll
    for (int q = 0; q < 2; ++q) {
        afr[q]  = sAs[(ti0 + q) * 64 + lane];
        rowb[q] = (ti0 + q) * 16 + ((lane >> 4) << 2);
        #pragma unroll
        for (int r = 0; r < 4; ++r) x2r[q * 4 + r] = na[rowb[q] + r];
    }

    u64 rp[8];
    #pragma unroll
    for (int i = 0; i < 8; ++i) rp[i] = ~0ull;

    const f32x4 zero = {0.f, 0.f, 0.f, 0.f};

    #pragma unroll 2
    for (int jj = 0; jj < NT; ++jj) {
        f16x8 bfr = sBs[jj * 64 + lane];
        const unsigned colg = (unsigned)(jj * 16 + (lane & 15));
        const float y2c = nb[colg];
        #pragma unroll
        for (int q = 0; q < 2; ++q) {
            f32x4 d4 = __builtin_amdgcn_mfma_f32_16x16x32_f16(afr[q], bfr, zero, 0, 0, 0);
            #pragma unroll
            for (int r = 0; r < 4; ++r) {
                float d = fmaxf(x2r[q * 4 + r] + y2c + d4[r], 0.f);   // ref order + clamp
                rp[q * 4 + r] = umin64(rp[q * 4 + r],
                                       (((u64)__float_as_uint(d)) << 32) | (u64)colg);
            }
        }
    }

    #pragma unroll
    for (int q = 0; q < 2; ++q) {
        #pragma unroll
        for (int r = 0; r < 4; ++r) {
            u64 v = rp[q * 4 + r];
            v = umin64(v, (u64)__shfl_xor((unsigned long long)v, 1, 64));
            v = umin64(v, (u64)__shfl_xor((unsigned long long)v, 2, 64));
            v = umin64(v, (u64)__shfl_xor((unsigned long long)v, 4, 64));
            v = umin64(v, (u64)__shfl_xor((unsigned long long)v, 8, 64));
            if ((lane & 15) == 0) out_arr[rowb[q] + r] = v;
        }
    }
}

// One block per batch element, 1024 threads = 16 waves. Two transposed passes:
// pass1 rows (input vs pred), pass2 cols via operand swap (valid: A/B fragments
// share the (lane,k) layout; hi/lo pairing covers {hi,lo}^2 once each either way).
__global__ __launch_bounds__(1024)
void loss_kernel(const float* __restrict__ kine_input,
                 const float* __restrict__ class_input,
                 const float* __restrict__ kine_pred,
                 const float* __restrict__ class_pred,
                 const float* __restrict__ mu,
                 const float* __restrict__ log_var,
                 float* __restrict__ out)
{
    const int b    = (int)blockIdx.x;
    const int t    = (int)threadIdx.x;
    const int lane = t & 63;
    const int wave = t >> 6;

    __shared__ f16x8 sA[NT * 64];        // A' fragments (input side), 32 KB
    __shared__ f16x8 sB[NT * 64];        // B' fragments (pred side),  32 KB
    __shared__ float sx2[NN], sy2[NN];   // squared norms
    __shared__ u64   row_arr[NN];        // row minima (unique writer)
    __shared__ u64   col_arr[NN];        // col minima (unique writer)
    __shared__ float red[16];
    __shared__ float s_kl;
    __shared__ int   hist_in[DD], hist_pr[DD];

    if (t < DD) { hist_in[t] = 0; hist_pr[t] = 0; }

    // ---- stage fragments: slot s = rep*1024+t -> side|ti|lane ----
    // lane ln: row/col = ti*16 + (ln&15), kg = ln>>4, k = kg*8+e (k<16 used).
    // A side: kg==0 -> hi(-2x), kg==1 -> lo. B side: e<4 -> hi(y), e>=4 -> lo.
    #pragma unroll
    for (int rep = 0; rep < 4; ++rep) {
        const int s    = rep * 1024 + t;
        const int side = s >> 11;
        const int ti   = (s >> 6) & 31;
        const int ln   = s & 63;
        const int row  = ti * 16 + (ln & 15);
        const int kg   = ln >> 4;
        const float* P = side ? kine_pred : kine_input;
        float4 pt = *reinterpret_cast<const float4*>(P + ((size_t)b * NN + row) * 4);
        float n = pt.x*pt.x + pt.y*pt.y + pt.z*pt.z + pt.w*pt.w;
        if (kg == 0) { (side ? sy2 : sx2)[row] = n; }
        float w[4];
        if (side == 0) { w[0] = -2.f*pt.x; w[1] = -2.f*pt.y; w[2] = -2.f*pt.z; w[3] = -2.f*pt.w; }
        else           { w[0] =      pt.x; w[1] =      pt.y; w[2] =      pt.z; w[3] =      pt.w; }
        _Float16 hi[4], lo[4];
        #pragma unroll
        for (int c = 0; c < 4; ++c) { hi[c] = (_Float16)w[c]; lo[c] = (_Float16)(w[c] - (float)hi[c]); }
        f16x8 hv;
        #pragma unroll
        for (int e = 0; e < 8; ++e) {
            _Float16 v = (_Float16)0.f;
            if (kg < 2) {
                const int c = e & 3;
                if (side == 0) v = (kg == 0) ? hi[c] : lo[c];
                else           v = (e < 4) ? hi[c] : lo[c];
            }
            hv[e] = v;
        }
        (side ? sB : sA)[ti * 64 + ln] = hv;
    }
    __syncthreads();

    // ---- pass 1: input rows vs pred cols; pass 2: transposed ----
    min_pass(sA, sB, sx2, sy2, row_arr, wave, lane);
    min_pass(sB, sA, sy2, sx2, col_arr, wave, lane);

    // ---- histograms (labels independent of argmins) + KL ----
    {
        const float* cls = (t < NN) ? class_input : class_pred;
        const int r = t & (NN - 1);
        const float* rowp = cls + ((size_t)b * NN + r) * DD;
        float mx = rowp[0]; int lab = 0;
        #pragma unroll
        for (int d2 = 1; d2 < DD; ++d2) { float v = rowp[d2]; if (v > mx) { mx = v; lab = d2; } }  // argmax(exp)==argmax
        atomicAdd((t < NN) ? &hist_in[lab] : &hist_pr[lab], 1);
    }
    if (t < 64) {
        float v = 0.f;
        if (t < LL) {
            float m_ = mu[(size_t)b * LL + t];
            float lv = log_var[(size_t)b * LL + t];
            v = 1.f + lv - m_ * m_ - expf(lv);
        }
        #pragma unroll
        for (int off = 32; off > 0; off >>= 1) v += __shfl_down(v, off, 64);
        if (t == 0) s_kl = -0.5f * v;
    }
    __syncthreads();

    // ---- epilogue: thread t -> (pass p, row lr); unpack, class dot ----
    float part;
    {
        const int p  = t >> 9;
        const int lr = t & (NN - 1);
        const u64 e = p ? col_arr[lr] : row_arr[lr];
        const int idx = (int)(e & 511u);
        const float dmin = __uint_as_float((unsigned)(e >> 32));
        const float* own = (p ? class_pred  : class_input) + ((size_t)b * NN + lr) * DD;
        const float* oth = (p ? class_input : class_pred)  + ((size_t)b * NN + idx) * DD;
        float dot = 0.f;
        #pragma unroll
        for (int d2 = 0; d2 < DD; ++d2) dot += own[d2] * oth[d2];
        part = dmin - dot;   // chamfer + (-1)*class dot (W=1)
    }
    #pragma unroll
    for (int off = 32; off > 0; off >>= 1) part += __shfl_down(part, off, 64);
    if (lane == 0) red[wave] = part;
    __syncthreads();

    if (t == 0) {
        float sum = 0.f;
        #pragma unroll
        for (int w2 = 0; w2 < 16; ++w2) sum += red[w2];
        float cnum = 0.f;
        #pragma unroll
        for (int c = 0; c < DD; ++c) {
            float diff = fabsf((float)(hist_pr[c] - hist_in[c]));
            float wgt = (c == 0) ? 2.0f : ((c == DD - 1) ? 100.0f : 1.0f);
            cnum += wgt * diff;
        }
        out[b] = 0.99f * (sum + 0.001f * cnum) + 0.01f * s_kl;
    }
}

extern "C" void kernel_launch(void* const* d_in, const int* in_sizes, int n_in,
                              void* d_out, int out_size, void* d_ws, size_t ws_size,
                              hipStream_t stream) {
    const float* kine_input  = (const float*)d_in[0];
    const float* class_input = (const float*)d_in[1];
    const float* kine_pred   = (const float*)d_in[2];
    const float* class_pred  = (const float*)d_in[3];
    const float* mu          = (const float*)d_in[4];
    const float* log_var     = (const float*)d_in[5];
    float* out = (float*)d_out;

    loss_kernel<<<256, 1024, 0, stream>>>(kine_input, class_input, kine_pred,
                                          class_pred, mu, log_var, out);
}

// Round 8
// 28.867 us; speedup vs baseline: 1.3731x; 1.3731x over previous
//
#include <hip/hip_runtime.h>

#define NN 512
#define DD 9
#define LL 32
#define NT 32   // 16x16 tiles per dimension

typedef _Float16 f16x8 __attribute__((ext_vector_type(8)));
typedef float    f32x4 __attribute__((ext_vector_type(4)));

// Register-only min scan: wave owns row-tiles {2w, 2w+1} of the "a side",
// scans all 32 "b side" tiles. MFMA (16x16x32 f16) emits the COMPLETE distance
// (cross term hi/lo-split in k0..15, norms folded at k16..19). Tracking is
// cmp + dual-cndmask (3 ops/cell); per-lane scan order is ascending col, so
// strict < keeps the first index; the 16-lane butterfly does an exact
// lexicographic (d, col) merge. Unique writer per row, no atomics.
__device__ __forceinline__ void min_scan(const f16x8* __restrict__ sAs,
                                         const f16x8* __restrict__ sBs,
                                         float* __restrict__ out_d,
                                         int*  __restrict__ out_i,
                                         int wave, int lane)
{
    const int ti0 = wave * 2;
    const f16x8 afr0 = sAs[ti0 * 64 + lane];
    const f16x8 afr1 = sAs[(ti0 + 1) * 64 + lane];
    const int rowb0 = ti0 * 16 + ((lane >> 4) << 2);

    float    bd[8];
    unsigned bc[8];
    #pragma unroll
    for (int i = 0; i < 8; ++i) { bd[i] = 1e30f; bc[i] = 0; }

    const f32x4 zero = {0.f, 0.f, 0.f, 0.f};
    unsigned colg = (unsigned)(lane & 15);

    #pragma unroll 2
    for (int jj = 0; jj < NT; ++jj) {
        f16x8 bfr = sBs[jj * 64 + lane];
        f32x4 d0 = __builtin_amdgcn_mfma_f32_16x16x32_f16(afr0, bfr, zero, 0, 0, 0);
        f32x4 d1 = __builtin_amdgcn_mfma_f32_16x16x32_f16(afr1, bfr, zero, 0, 0, 0);
        #pragma unroll
        for (int r = 0; r < 4; ++r) {
            if (d0[r] < bd[r])     { bd[r]     = d0[r]; bc[r]     = colg; }
            if (d1[r] < bd[4 + r]) { bd[4 + r] = d1[r]; bc[4 + r] = colg; }
        }
        colg += 16;
    }

    #pragma unroll
    for (int q = 0; q < 2; ++q) {
        #pragma unroll
        for (int r = 0; r < 4; ++r) {
            float d = bd[q * 4 + r]; unsigned c = bc[q * 4 + r];
            #pragma unroll
            for (int off = 1; off < 16; off <<= 1) {
                float    pd = __shfl_xor(d, off, 64);
                unsigned pc = (unsigned)__shfl_xor((int)c, off, 64);
                bool take = (pd < d) || (pd == d && pc < c);
                d = take ? pd : d;
                c = take ? pc : c;
            }
            if ((lane & 15) == 0) {
                const int row = rowb0 + q * 16 + r;
                out_d[row] = fmaxf(d, 0.f);   // clamp commutes with min
                out_i[row] = (int)c;
            }
        }
    }
}

// One block per batch element, 1024 threads = 16 waves. Two transposed scans
// (operand swap valid: hi/lo pairing covers {hi,lo}^2 once in both roles;
// norm slots k16..19 are symmetric under the swap by construction).
__global__ __launch_bounds__(1024, 4)
void loss_kernel(const float* __restrict__ kine_input,
                 const float* __restrict__ class_input,
                 const float* __restrict__ kine_pred,
                 const float* __restrict__ class_pred,
                 const float* __restrict__ mu,
                 const float* __restrict__ log_var,
                 float* __restrict__ out)
{
    const int b    = (int)blockIdx.x;
    const int t    = (int)threadIdx.x;
    const int lane = t & 63;
    const int wave = t >> 6;

    __shared__ f16x8 sA[NT * 64];     // A' fragments (input side), 32 KB
    __shared__ f16x8 sB[NT * 64];     // B' fragments (pred side),  32 KB
    __shared__ float row_d[NN], col_d[NN];
    __shared__ int   row_i[NN], col_i[NN];
    __shared__ float red[16];
    __shared__ float s_kl;
    __shared__ int   hist_in[DD], hist_pr[DD];

    if (t < DD) { hist_in[t] = 0; hist_pr[t] = 0; }

    // ---- stage fragments: slot s = rep*1024+t -> side|ti|lane ----
    // lane ln: row/col = ti*16 + (ln&15), kg = ln>>4, k = kg*8+e.
    // k0..15 cross term: A kg0=hi(-2x) kg1=lo(-2x); B e<4=hi(y) else lo(y).
    // k16..19 norms: (A,B) = (1,y2hi),(1,y2lo),(x2hi,1),(x2lo,1).
    #pragma unroll
    for (int rep = 0; rep < 4; ++rep) {
        const int s    = rep * 1024 + t;
        const int side = s >> 11;
        const int ti   = (s >> 6) & 31;
        const int ln   = s & 63;
        const int row  = ti * 16 + (ln & 15);
        const int kg   = ln >> 4;
        const float* P = side ? kine_pred : kine_input;
        float4 pt = *reinterpret_cast<const float4*>(P + ((size_t)b * NN + row) * 4);
        float n = pt.x*pt.x + pt.y*pt.y + pt.z*pt.z + pt.w*pt.w;
        float w[4];
        if (side == 0) { w[0] = -2.f*pt.x; w[1] = -2.f*pt.y; w[2] = -2.f*pt.z; w[3] = -2.f*pt.w; }
        else           { w[0] =      pt.x; w[1] =      pt.y; w[2] =      pt.z; w[3] =      pt.w; }
        _Float16 hi[4], lo[4];
        #pragma unroll
        for (int c = 0; c < 4; ++c) { hi[c] = (_Float16)w[c]; lo[c] = (_Float16)(w[c] - (float)hi[c]); }
        const _Float16 nhi = (_Float16)n;
        const _Float16 nlo = (_Float16)(n - (float)nhi);
        const _Float16 one = (_Float16)1.f;
        f16x8 hv;
        #pragma unroll
        for (int e = 0; e < 8; ++e) {
            _Float16 v = (_Float16)0.f;
            if (kg < 2) {
                const int c = e & 3;
                if (side == 0) v = (kg == 0) ? hi[c] : lo[c];
                else           v = (e < 4) ? hi[c] : lo[c];
            } else if (kg == 2 && e < 4) {
                if (side == 0) v = (e == 0 || e == 1) ? one : ((e == 2) ? nhi : nlo);
                else           v = (e == 0) ? nhi : ((e == 1) ? nlo : one);
            }
            hv[e] = v;
        }
        (side ? sB : sA)[ti * 64 + ln] = hv;
    }
    __syncthreads();

    // ---- pass 1: input rows vs pred cols; pass 2: transposed ----
    min_scan(sA, sB, row_d, row_i, wave, lane);
    min_scan(sB, sA, col_d, col_i, wave, lane);

    // ---- histograms (labels independent of argmins) + KL ----
    {
        const float* cls = (t < NN) ? class_input : class_pred;
        const int r = t & (NN - 1);
        const float* rowp = cls + ((size_t)b * NN + r) * DD;
        float mx = rowp[0]; int lab = 0;
        #pragma unroll
        for (int d2 = 1; d2 < DD; ++d2) { float v = rowp[d2]; if (v > mx) { mx = v; lab = d2; } }  // argmax(exp)==argmax
        atomicAdd((t < NN) ? &hist_in[lab] : &hist_pr[lab], 1);
    }
    if (t < 64) {
        float v = 0.f;
        if (t < LL) {
            float m_ = mu[(size_t)b * LL + t];
            float lv = log_var[(size_t)b * LL + t];
            v = 1.f + lv - m_ * m_ - expf(lv);
        }
        #pragma unroll
        for (int off = 32; off > 0; off >>= 1) v += __shfl_down(v, off, 64);
        if (t == 0) s_kl = -0.5f * v;
    }
    __syncthreads();

    // ---- epilogue: thread t -> (pass p, row lr); class dot via argmin gather ----
    float part;
    {
        const int p  = t >> 9;
        const int lr = t & (NN - 1);
        const float dmin = p ? col_d[lr] : row_d[lr];
        const int   idx  = p ? col_i[lr] : row_i[lr];
        const float* own = (p ? class_pred  : class_input) + ((size_t)b * NN + lr) * DD;
        const float* oth = (p ? class_input : class_pred)  + ((size_t)b * NN + idx) * DD;
        float dot = 0.f;
        #pragma unroll
        for (int d2 = 0; d2 < DD; ++d2) dot += own[d2] * oth[d2];
        part = dmin - dot;   // chamfer + (-1)*class dot (W=1)
    }
    #pragma unroll
    for (int off = 32; off > 0; off >>= 1) part += __shfl_down(part, off, 64);
    if (lane == 0) red[wave] = part;
    __syncthreads();

    if (t == 0) {
        float sum = 0.f;
        #pragma unroll
        for (int w2 = 0; w2 < 16; ++w2) sum += red[w2];
        float cnum = 0.f;
        #pragma unroll
        for (int c = 0; c < DD; ++c) {
            float diff = fabsf((float)(hist_pr[c] - hist_in[c]));
            float wgt = (c == 0) ? 2.0f : ((c == DD - 1) ? 100.0f : 1.0f);
            cnum += wgt * diff;
        }
        out[b] = 0.99f * (sum + 0.001f * cnum) + 0.01f * s_kl;
    }
}

extern "C" void kernel_launch(void* const* d_in, const int* in_sizes, int n_in,
                              void* d_out, int out_size, void* d_ws, size_t ws_size,
                              hipStream_t stream) {
    const float* kine_input  = (const float*)d_in[0];
    const float* class_input = (const float*)d_in[1];
    const float* kine_pred   = (const float*)d_in[2];
    const float* class_pred  = (const float*)d_in[3];
    const float* mu          = (const float*)d_in[4];
    const float* log_var     = (const float*)d_in[5];
    float* out = (float*)d_out;

    loss_kernel<<<256, 1024, 0, stream>>>(kine_input, class_input, kine_pred,
                                          class_pred, mu, log_var, out);
}

// Round 9
// 24.652 us; speedup vs baseline: 1.6079x; 1.1710x over previous
//
#include <hip/hip_runtime.h>

#define NN 512
#define DD 9
#define LL 32
#define NT 32   // 16x16 tiles per dimension

typedef _Float16 f16x8 __attribute__((ext_vector_type(8)));
typedef float    f32x4 __attribute__((ext_vector_type(4)));
typedef unsigned long long u64;

__device__ __forceinline__ u64 umin64(u64 a, u64 b) { return a < b ? a : b; }

// Scan: pass-local wave wp owns 4 row-tiles {4wp..4wp+3} of the "a side",
// scans all 32 "b side" tiles (1 ds_read_b128 feeds 4 MFMAs). MFMA emits the
// complete distance (cross hi/lo split k0..15, norms folded k16..19).
// Tracking: cmp + dual-cndmask on raw d (3 ops/cell), ascending col -> first
// index. One xor-8 butterfly step merges 16 col-groups to 8, then active
// lanes write u64 lex keys (clamped dbits<<32)|col to part[row][group].
__device__ __forceinline__ void min_scan4(const f16x8* __restrict__ sAs,
                                          const f16x8* __restrict__ sBs,
                                          u64 (* __restrict__ part)[9],
                                          int wp, int lane)
{
    const int ti0 = wp * 4;
    f16x8 afr[4];
    #pragma unroll
    for (int q = 0; q < 4; ++q) afr[q] = sAs[(ti0 + q) * 64 + lane];

    float    bd[16];
    unsigned bc[16];
    #pragma unroll
    for (int i = 0; i < 16; ++i) { bd[i] = 1e30f; bc[i] = 0; }

    const f32x4 zero = {0.f, 0.f, 0.f, 0.f};
    unsigned colg = (unsigned)(lane & 15);

    #pragma unroll 2
    for (int jj = 0; jj < NT; ++jj) {
        f16x8 bfr = sBs[jj * 64 + lane];
        #pragma unroll
        for (int q = 0; q < 4; ++q) {
            f32x4 d4 = __builtin_amdgcn_mfma_f32_16x16x32_f16(afr[q], bfr, zero, 0, 0, 0);
            #pragma unroll
            for (int r = 0; r < 4; ++r) {
                if (d4[r] < bd[q * 4 + r]) { bd[q * 4 + r] = d4[r]; bc[q * 4 + r] = colg; }
            }
        }
        colg += 16;
    }

    // one butterfly step: merge col-groups g and g+8 (exact lex on (d, col))
    #pragma unroll
    for (int i = 0; i < 16; ++i) {
        float    pd = __shfl_xor(bd[i], 8, 64);
        unsigned pc = (unsigned)__shfl_xor((int)bc[i], 8, 64);
        bool take = (pd < bd[i]) || (pd == bd[i] && pc < bc[i]);
        bd[i] = take ? pd : bd[i];
        bc[i] = take ? pc : bc[i];
    }
    if ((lane & 8) == 0) {
        const int g  = lane & 7;
        const int rb = ((lane >> 4) << 2);
        #pragma unroll
        for (int q = 0; q < 4; ++q) {
            #pragma unroll
            for (int r = 0; r < 4; ++r) {
                const int row = (ti0 + q) * 16 + rb + r;
                const float dc = fmaxf(bd[q * 4 + r], 0.f);   // clamp at pack (ref semantics)
                part[row][g] = (((u64)__float_as_uint(dc)) << 32) | (u64)bc[q * 4 + r];
            }
        }
    }
}

// One block per batch, 1024 threads = 16 waves. Waves 0-7: pass 1 (input rows
// vs pred cols); waves 8-15: pass 2 operand-swapped (valid: hi/lo pairing
// covers {hi,lo}^2 once in both roles; norm slots symmetric by construction).
__global__ __launch_bounds__(1024, 8)
void loss_kernel(const float* __restrict__ kine_input,
                 const float* __restrict__ class_input,
                 const float* __restrict__ kine_pred,
                 const float* __restrict__ class_pred,
                 const float* __restrict__ mu,
                 const float* __restrict__ log_var,
                 float* __restrict__ out)
{
    const int b    = (int)blockIdx.x;
    const int t    = (int)threadIdx.x;
    const int lane = t & 63;
    const int wave = t >> 6;

    __shared__ f16x8 sA[NT * 64];        // A' fragments (input side), 32 KB
    __shared__ f16x8 sB[NT * 64];        // B' fragments (pred side),  32 KB
    __shared__ u64   part[2][NN][9];     // lex-key partials, 72 KB (stride 72B: 2-way free)
    __shared__ float red[16];
    __shared__ float s_kl;
    __shared__ int   hist_in[DD], hist_pr[DD];

    if (t < DD) { hist_in[t] = 0; hist_pr[t] = 0; }

    // ---- stage fragments: slot s = rep*1024+t -> side|ti|lane ----
    // lane ln: row/col = ti*16 + (ln&15), kg = ln>>4, k = kg*8+e.
    // k0..15 cross term: A kg0=hi(-2x) kg1=lo(-2x); B e<4=hi(y) else lo(y).
    // k16..19 norms: (A,B) = (1,y2hi),(1,y2lo),(x2hi,1),(x2lo,1).
    #pragma unroll
    for (int rep = 0; rep < 4; ++rep) {
        const int s    = rep * 1024 + t;
        const int side = s >> 11;
        const int ti   = (s >> 6) & 31;
        const int ln   = s & 63;
        const int row  = ti * 16 + (ln & 15);
        const int kg   = ln >> 4;
        const float* P = side ? kine_pred : kine_input;
        float4 pt = *reinterpret_cast<const float4*>(P + ((size_t)b * NN + row) * 4);
        float n = pt.x*pt.x + pt.y*pt.y + pt.z*pt.z + pt.w*pt.w;
        float w[4];
        if (side == 0) { w[0] = -2.f*pt.x; w[1] = -2.f*pt.y; w[2] = -2.f*pt.z; w[3] = -2.f*pt.w; }
        else           { w[0] =      pt.x; w[1] =      pt.y; w[2] =      pt.z; w[3] =      pt.w; }
        _Float16 hi[4], lo[4];
        #pragma unroll
        for (int c = 0; c < 4; ++c) { hi[c] = (_Float16)w[c]; lo[c] = (_Float16)(w[c] - (float)hi[c]); }
        const _Float16 nhi = (_Float16)n;
        const _Float16 nlo = (_Float16)(n - (float)nhi);
        const _Float16 one = (_Float16)1.f;
        f16x8 hv;
        #pragma unroll
        for (int e = 0; e < 8; ++e) {
            _Float16 v = (_Float16)0.f;
            if (kg < 2) {
                const int c = e & 3;
                if (side == 0) v = (kg == 0) ? hi[c] : lo[c];
                else           v = (e < 4) ? hi[c] : lo[c];
            } else if (kg == 2 && e < 4) {
                if (side == 0) v = (e == 0 || e == 1) ? one : ((e == 2) ? nhi : nlo);
                else           v = (e == 0) ? nhi : ((e == 1) ? nlo : one);
            }
            hv[e] = v;
        }
        (side ? sB : sA)[ti * 64 + ln] = hv;
    }
    __syncthreads();

    // ---- concurrent transposed scans on wave halves ----
    if (wave < 8) min_scan4(sA, sB, part[0], wave,     lane);
    else          min_scan4(sB, sA, part[1], wave - 8, lane);

    // ---- histograms (labels independent of argmins) + KL ----
    {
        const float* cls = (t < NN) ? class_input : class_pred;
        const int r = t & (NN - 1);
        const float* rowp = cls + ((size_t)b * NN + r) * DD;
        float mx = rowp[0]; int lab = 0;
        #pragma unroll
        for (int d2 = 1; d2 < DD; ++d2) { float v = rowp[d2]; if (v > mx) { mx = v; lab = d2; } }  // argmax(exp)==argmax
        atomicAdd((t < NN) ? &hist_in[lab] : &hist_pr[lab], 1);
    }
    if (t < 64) {
        float v = 0.f;
        if (t < LL) {
            float m_ = mu[(size_t)b * LL + t];
            float lv = log_var[(size_t)b * LL + t];
            v = 1.f + lv - m_ * m_ - expf(lv);
        }
        #pragma unroll
        for (int off = 32; off > 0; off >>= 1) v += __shfl_down(v, off, 64);
        if (t == 0) s_kl = -0.5f * v;
    }
    __syncthreads();

    // ---- merge 8 groups + epilogue: thread t -> (pass p, row lr) ----
    float partsum;
    {
        const int p  = t >> 9;
        const int lr = t & (NN - 1);
        u64 e = part[p][lr][0];
        #pragma unroll
        for (int g = 1; g < 8; ++g) e = umin64(e, part[p][lr][g]);
        const int   idx  = (int)(unsigned)(e & 0xFFFFFFFFull);
        const float dmin = __uint_as_float((unsigned)(e >> 32));
        const float* own = (p ? class_pred  : class_input) + ((size_t)b * NN + lr) * DD;
        const float* oth = (p ? class_input : class_pred)  + ((size_t)b * NN + idx) * DD;
        float dot = 0.f;
        #pragma unroll
        for (int d2 = 0; d2 < DD; ++d2) dot += own[d2] * oth[d2];
        partsum = dmin - dot;   // chamfer + (-1)*class dot (W=1)
    }
    #pragma unroll
    for (int off = 32; off > 0; off >>= 1) partsum += __shfl_down(partsum, off, 64);
    if (lane == 0) red[wave] = partsum;
    __syncthreads();

    if (t == 0) {
        float sum = 0.f;
        #pragma unroll
        for (int w2 = 0; w2 < 16; ++w2) sum += red[w2];
        float cnum = 0.f;
        #pragma unroll
        for (int c = 0; c < DD; ++c) {
            float diff = fabsf((float)(hist_pr[c] - hist_in[c]));
            float wgt = (c == 0) ? 2.0f : ((c == DD - 1) ? 100.0f : 1.0f);
            cnum += wgt * diff;
        }
        out[b] = 0.99f * (sum + 0.001f * cnum) + 0.01f * s_kl;
    }
}

extern "C" void kernel_launch(void* const* d_in, const int* in_sizes, int n_in,
                              void* d_out, int out_size, void* d_ws, size_t ws_size,
                              hipStream_t stream) {
    const float* kine_input  = (const float*)d_in[0];
    const float* class_input = (const float*)d_in[1];
    const float* kine_pred   = (const float*)d_in[2];
    const float* class_pred  = (const float*)d_in[3];
    const float* mu          = (const float*)d_in[4];
    const float* log_var     = (const float*)d_in[5];
    float* out = (float*)d_out;

    loss_kernel<<<256, 1024, 0, stream>>>(kine_input, class_input, kine_pred,
                                          class_pred, mu, log_var, out);
}